// Round 12
// baseline (2587.943 us; speedup 1.0000x reference)
//
#include <hip/hip_runtime.h>

// Problem: x (B=4, C=256, D=32, H=64, W=64) fp32.
// 1) reflect-pad(2) + per-(b,c) mean  == weighted sum over original x
// 2) LSTMCell scan over C=256 channels (B=4, hidden=32, input=1)
// 3) gate[b,c] = sigmoid(h_c . gate_w + gate_b);  out = x * gate[b,c]
//
// R12: two kernels. K1 = mean (full occupancy). K2 = fused lstm+scale:
// ticket 0 -> LSTM producer (4 waves = 4 batches, streams gates with
// release); tickets 1..2048 -> scale half-channels, each waits (acquire,
// s_sleep-throttled) for its gate then streams 256KB with NT stores.
// Producer is always a RUNNING block (ticket, not blockIdx) -> no deadlock
// under any dispatch order (R10 lesson). LSTM hides under the scale stream.

#define MEAN_DEN (1.0f / 166464.0f)   // 36*68*68

typedef unsigned int uint;
typedef float f32x4 __attribute__((ext_vector_type(4)));
typedef float f32x2 __attribute__((ext_vector_type(2)));

__device__ __forceinline__ float sigf(float x) {
    return 1.0f / (1.0f + __expf(-x));
}
__device__ __forceinline__ float tanh_fast(float x) {
    return fmaf(2.0f, sigf(2.0f * x), -1.0f);   // tanh(x) = 2*sigmoid(2x) - 1
}
__device__ __forceinline__ uint ld_acq(const uint* p) {
    return __hip_atomic_load(p, __ATOMIC_ACQUIRE, __HIP_MEMORY_SCOPE_AGENT);
}
__device__ __forceinline__ void st_rel(uint* p, uint v) {
    __hip_atomic_store(p, v, __ATOMIC_RELEASE, __HIP_MEMORY_SCOPE_AGENT);
}

// ---------- Kernel 1: weighted half-channel partial sums ----------
// 2048 blocks (8/CU, 100% occupancy); 8 independent loads in flight/thread.
__global__ __launch_bounds__(256) void mean_kernel(const float* __restrict__ x,
                                                   float* __restrict__ part) {
    const int bid = blockIdx.x;
    const int ch = bid >> 1, half = bid & 1;
    const f32x4* __restrict__ p = (const f32x4*)x + (size_t)ch * 32768 + half * 16384;
    const int base = half * 16384;
    const int tid = threadIdx.x;

    float s0 = 0.0f, s1 = 0.0f, s2 = 0.0f, s3 = 0.0f;
#pragma unroll
    for (int g = 0; g < 8; g++) {
        f32x4 v[8];
#pragma unroll
        for (int u = 0; u < 8; u++) v[u] = p[g * 2048 + u * 256 + tid];
#pragma unroll
        for (int u = 0; u < 8; u++) {
            const int i = base + g * 2048 + u * 256 + tid;
            const int q = i & 15;             // f4 index within W-row
            const int hh = (i >> 4) & 63;
            const int d = i >> 10;
            float t = (v[u].x + v[u].y) + (v[u].z + v[u].w);
            if (q == 0 || q == 15) t += v[u].y + v[u].z;   // W 1,2,61,62 doubled
            const float wd = ((d == 1) | (d == 2) | (d == 29) | (d == 30)) ? 2.0f : 1.0f;
            const float wh = ((hh == 1) | (hh == 2) | (hh == 61) | (hh == 62)) ? 2.0f : 1.0f;
            const float w = wd * wh;
            if ((u & 3) == 0)      s0 = fmaf(w, t, s0);
            else if ((u & 3) == 1) s1 = fmaf(w, t, s1);
            else if ((u & 3) == 2) s2 = fmaf(w, t, s2);
            else                   s3 = fmaf(w, t, s3);
        }
    }
    float sum = (s0 + s1) + (s2 + s3);

    __shared__ float red[256];
    red[tid] = sum;
    __syncthreads();
    for (int s = 128; s > 0; s >>= 1) {
        if (tid < s) red[tid] += red[tid + s];
        __syncthreads();
    }
    if (tid == 0) part[bid] = red[0];
}

// ---------- Kernel 2: fused LSTM producer + scale consumers ----------
#define RL(v, k) __builtin_bit_cast(float, \
    __builtin_amdgcn_readlane(__builtin_bit_cast(int, (v)), (k)))
#define DW(k) const float w0_##k = W_hh[r0 * 32 + (k)]; \
              const float w1_##k = W_hh[r1 * 32 + (k)];
#define GK(k, A0, A1) { const float hk = RL(h, k); \
                A0 = fmaf(hk, w0_##k, A0); A1 = fmaf(hk, w1_##k, A1); }

// ws layout (floats): [0] ticket(uint) | [16..20) gprog(uint) | [256..1280)
// gates | [2048..4096) part (written by K1)
__global__ __launch_bounds__(256) void gate_scale_kernel(
    const float* __restrict__ x,
    const float* __restrict__ W_ih, const float* __restrict__ W_hh,
    const float* __restrict__ b_ih, const float* __restrict__ b_hh,
    const float* __restrict__ gate_w, const float* __restrict__ gate_b,
    float* __restrict__ out, float* __restrict__ ws)
{
    uint*  ctrl  = (uint*)ws;            // [0] ticket
    uint*  gprog = (uint*)ws + 16;       // [16..20) per-batch progress
    float* gates = ws + 256;             // 1024 floats
    const float* part = ws + 2048;       // 2048 floats (from K1)

    __shared__ uint s_t;
    __shared__ float s_g;
    __shared__ float cs[4][256];

    const int tid = threadIdx.x;
    if (tid == 0)
        s_t = __hip_atomic_fetch_add(ctrl, 1u, __ATOMIC_RELAXED,
                                     __HIP_MEMORY_SCOPE_AGENT);
    __syncthreads();
    const uint T = s_t;

    if (T == 0u) {
        // ---- LSTM producer: 4 waves, wave b = batch b; gates streamed ----
        const int b = tid >> 6, l = tid & 63;
        const int r0 = l, r1 = l + 64;
        const float wih0 = W_ih[r0], wih1 = W_ih[r1];
        const float bias0 = b_ih[r0] + b_hh[r0];
        const float bias1 = b_ih[r1] + b_hh[r1];
        DW(0)  DW(1)  DW(2)  DW(3)  DW(4)  DW(5)  DW(6)  DW(7)
        DW(8)  DW(9)  DW(10) DW(11) DW(12) DW(13) DW(14) DW(15)
        DW(16) DW(17) DW(18) DW(19) DW(20) DW(21) DW(22) DW(23)
        DW(24) DW(25) DW(26) DW(27) DW(28) DW(29) DW(30) DW(31)
        const float gwl = gate_w[l & 31];
        const float gb = gate_b[0];

        // wave-local channel means (no cross-wave sharing -> no barrier)
        const f32x2* __restrict__ p2 = (const f32x2*)part + b * 256;
#pragma unroll
        for (int j = 0; j < 4; j++) {
            const int cch = j * 64 + l;
            f32x2 pr = p2[cch];
            cs[b][cch] = (pr.x + pr.y) * MEAN_DEN;
        }

        float h = 0.0f, cst = 0.0f;
        for (int t = 0; t < 256; t++) {
            const float inp = cs[b][t];
            float a0 = fmaf(inp, wih0, bias0), b0 = 0.f, c0 = 0.f, d0 = 0.f;
            float a1 = fmaf(inp, wih1, bias1), b1 = 0.f, c1 = 0.f, d1 = 0.f;
            GK(0,a0,a1)  GK(1,b0,b1)  GK(2,c0,c1)  GK(3,d0,d1)
            GK(4,a0,a1)  GK(5,b0,b1)  GK(6,c0,c1)  GK(7,d0,d1)
            GK(8,a0,a1)  GK(9,b0,b1)  GK(10,c0,c1) GK(11,d0,d1)
            GK(12,a0,a1) GK(13,b0,b1) GK(14,c0,c1) GK(15,d0,d1)
            GK(16,a0,a1) GK(17,b0,b1) GK(18,c0,c1) GK(19,d0,d1)
            GK(20,a0,a1) GK(21,b0,b1) GK(22,c0,c1) GK(23,d0,d1)
            GK(24,a0,a1) GK(25,b0,b1) GK(26,c0,c1) GK(27,d0,d1)
            GK(28,a0,a1) GK(29,b0,b1) GK(30,c0,c1) GK(31,d0,d1)
            const float z0 = (a0 + b0) + (c0 + d0);
            const float z1 = (a1 + b1) + (c1 + d1);
            float zf, zo;
#if __has_builtin(__builtin_amdgcn_permlane32_swap)
            {
                auto ra = __builtin_amdgcn_permlane32_swap(
                    __builtin_bit_cast(uint, z0), __builtin_bit_cast(uint, z0), false, false);
                auto rb = __builtin_amdgcn_permlane32_swap(
                    __builtin_bit_cast(uint, z1), __builtin_bit_cast(uint, z1), false, false);
                zf = __builtin_bit_cast(float, ra[1]);
                zo = __builtin_bit_cast(float, rb[1]);
            }
#else
            zf = __shfl_xor(z0, 32);
            zo = __shfl_xor(z1, 32);
#endif
            // valid in lanes<32 only (high lanes: finite garbage, never read)
            cst = sigf(zf) * cst + sigf(z0) * tanh_fast(z1);
            h = sigf(zo) * tanh_fast(cst);
            // inline gate: sum over lanes 0..31 (xor masks <32 stay in half)
            float p = h * gwl;
            p += __shfl_xor(p, 1);  p += __shfl_xor(p, 2);  p += __shfl_xor(p, 4);
            p += __shfl_xor(p, 8);  p += __shfl_xor(p, 16);
            if (l == 0) {
                gates[b * 256 + t] = sigf(p + gb);   // plain store...
                st_rel(&gprog[b], (uint)(t + 1));    // ...then release
            }
        }
        return;
    }

    // ---- scale consumer: half-channel item = T-1 ----
    const int item = (int)T - 1;           // 0..2047
    const int bc = item >> 1, half = item & 1;
    const int b = bc >> 8, c = bc & 255;

    if (tid == 0) {
        while (ld_acq(&gprog[b]) <= (uint)c) __builtin_amdgcn_s_sleep(16);
        s_g = gates[bc];                   // read after acquire, broadcast via LDS
    }
    __syncthreads();
    const float g = s_g;

    const size_t off = (((size_t)bc) << 15) + (half << 14);
    const f32x4* __restrict__ xi = (const f32x4*)x + off;
    f32x4* __restrict__ oi = (f32x4*)out + off;
#pragma unroll
    for (int gr = 0; gr < 8; gr++) {
        f32x4 v[8];
#pragma unroll
        for (int u = 0; u < 8; u++) v[u] = xi[gr * 2048 + u * 256 + tid];
#pragma unroll
        for (int u = 0; u < 8; u++) {
            v[u] *= g;
            __builtin_nontemporal_store(v[u], &oi[gr * 2048 + u * 256 + tid]);
        }
    }
}

extern "C" void kernel_launch(void* const* d_in, const int* in_sizes, int n_in,
                              void* d_out, int out_size, void* d_ws, size_t ws_size,
                              hipStream_t stream) {
    const float* x      = (const float*)d_in[0];
    const float* W_ih   = (const float*)d_in[1];   // (128,1)
    const float* W_hh   = (const float*)d_in[2];   // (128,32)
    const float* b_ih   = (const float*)d_in[3];   // (128,)
    const float* b_hh   = (const float*)d_in[4];   // (128,)
    const float* gate_w = (const float*)d_in[5];   // (1,32)
    const float* gate_b = (const float*)d_in[6];   // (1,)
    float* out = (float*)d_out;
    float* ws  = (float*)d_ws;

    // reset ticket + gprog each call (capture-safe); part/gates are
    // rewritten before use every call.
    hipMemsetAsync(d_ws, 0, 256, stream);
    mean_kernel<<<2048, 256, 0, stream>>>(x, ws + 2048);
    gate_scale_kernel<<<2049, 256, 0, stream>>>(x, W_ih, W_hh, b_ih, b_hh,
                                                gate_w, gate_b, out, ws);
}

// Round 14
// 828.913 us; speedup vs baseline: 3.1221x; 3.1221x over previous
//
#include <hip/hip_runtime.h>

// Problem: x (B=4, C=256, D=32, H=64, W=64) fp32.
// 1) reflect-pad(2) + per-(b,c) mean  == weighted sum over original x
// 2) LSTMCell scan over C=256 channels (B=4, hidden=32, input=1)
// 3) gate[b,c] = sigmoid(h_c . gate_w + gate_b);  out = x * gate[b,c]
//
// R14: ONE plain kernel, 1024 blocks, CO-RESIDENCY GUARANTEED:
// __launch_bounds__(256,4) forces VGPR<=128 -> 4 blocks/CU -> all 1024
// blocks resident (R13 deadlocked because 2048 > resident capacity).
//   phase A: block = full channel (512KB) weighted mean, dual-stream
//            unroll-8 (16 loads in flight), done-counter ACQ_REL.
//   phase B: rank-1023 (last) block runs LSTM inline; ONE release store
//            to flag (R12 lesson: polled line written exactly once).
//   phase C: all blocks poll flag, scale own channel, NT stores
//            (R8 vs R11 A/B: NT -14us).

#define MEAN_DEN (1.0f / 166464.0f)   // 36*68*68

typedef unsigned int uint;
typedef float f32x4 __attribute__((ext_vector_type(4)));

__device__ __forceinline__ float sigf(float x) {
    return 1.0f / (1.0f + __expf(-x));
}
__device__ __forceinline__ float tanh_fast(float x) {
    return fmaf(2.0f, sigf(2.0f * x), -1.0f);   // tanh(x) = 2*sigmoid(2x) - 1
}
__device__ __forceinline__ uint ld_acq(const uint* p) {
    return __hip_atomic_load(p, __ATOMIC_ACQUIRE, __HIP_MEMORY_SCOPE_AGENT);
}
__device__ __forceinline__ void st_rel(uint* p, uint v) {
    __hip_atomic_store(p, v, __ATOMIC_RELEASE, __HIP_MEMORY_SCOPE_AGENT);
}

#define RL(v, k) __builtin_bit_cast(float, \
    __builtin_amdgcn_readlane(__builtin_bit_cast(int, (v)), (k)))
#define DW(k) const float w0_##k = W_hh[r0 * 32 + (k)]; \
              const float w1_##k = W_hh[r1 * 32 + (k)];
#define GK(k, A0, A1) { const float hk = RL(h, k); \
                A0 = fmaf(hk, w0_##k, A0); A1 = fmaf(hk, w1_##k, A1); }

// ws layout (floats): [0] done(uint) | [32] flag(uint) | [256..1280) gates
// | [2048..3072) part (per-channel means, pre-scaled)
__global__ __launch_bounds__(256, 4) void fused_kernel(
    const float* __restrict__ x,
    const float* __restrict__ W_ih, const float* __restrict__ W_hh,
    const float* __restrict__ b_ih, const float* __restrict__ b_hh,
    const float* __restrict__ gate_w, const float* __restrict__ gate_b,
    float* __restrict__ out, float* __restrict__ ws)
{
    uint*  done  = (uint*)ws;
    uint*  flag  = (uint*)ws + 32;
    float* gates = ws + 256;
    float* part  = ws + 2048;

    __shared__ float red[256];
    __shared__ uint s_rank;
    __shared__ float cs[4][256];

    const int ch  = blockIdx.x;          // 0..1023 == b*256 + c
    const int tid = threadIdx.x;
    const size_t off = (size_t)ch << 15;                     // f4 units

    // ---------------- phase A: weighted mean of full channel ----------------
    {
        const f32x4* __restrict__ p0 = (const f32x4*)x + off;           // half 0
        const f32x4* __restrict__ p1 = p0 + 16384;                      // half 1
        float s0 = 0.0f, s1 = 0.0f;
#pragma unroll
        for (int g = 0; g < 8; g++) {
            f32x4 v0[8], v1[8];
#pragma unroll
            for (int u = 0; u < 8; u++) {
                v0[u] = p0[g * 2048 + u * 256 + tid];
                v1[u] = p1[g * 2048 + u * 256 + tid];
            }
#pragma unroll
            for (int u = 0; u < 8; u++) {
                const int i0 = g * 2048 + u * 256 + tid;     // f4 idx, half 0
                const int i1 = i0 + 16384;                   // f4 idx, half 1
                {
                    const int q = i0 & 15, hh = (i0 >> 4) & 63, d = i0 >> 10;
                    float t = (v0[u].x + v0[u].y) + (v0[u].z + v0[u].w);
                    if (q == 0 || q == 15) t += v0[u].y + v0[u].z;
                    const float wd = ((d == 1) | (d == 2) | (d == 29) | (d == 30)) ? 2.f : 1.f;
                    const float wh = ((hh == 1) | (hh == 2) | (hh == 61) | (hh == 62)) ? 2.f : 1.f;
                    s0 = fmaf(wd * wh, t, s0);
                }
                {
                    const int q = i1 & 15, hh = (i1 >> 4) & 63, d = i1 >> 10;
                    float t = (v1[u].x + v1[u].y) + (v1[u].z + v1[u].w);
                    if (q == 0 || q == 15) t += v1[u].y + v1[u].z;
                    const float wd = ((d == 1) | (d == 2) | (d == 29) | (d == 30)) ? 2.f : 1.f;
                    const float wh = ((hh == 1) | (hh == 2) | (hh == 61) | (hh == 62)) ? 2.f : 1.f;
                    s1 = fmaf(wd * wh, t, s1);
                }
            }
        }
        red[tid] = s0 + s1;
        __syncthreads();
        for (int s = 128; s > 0; s >>= 1) {
            if (tid < s) red[tid] += red[tid + s];
            __syncthreads();
        }
        if (tid == 0) {
            part[ch] = red[0] * MEAN_DEN;
            s_rank = __hip_atomic_fetch_add(done, 1u, __ATOMIC_ACQ_REL,
                                            __HIP_MEMORY_SCOPE_AGENT);
        }
        __syncthreads();
    }

    // ---------------- phase B: last block runs the LSTM inline ----------------
    if (s_rank == 1023u) {
        const int b = tid >> 6, l = tid & 63;    // wave b = batch b
        const int r0 = l, r1 = l + 64;
        const float wih0 = W_ih[r0], wih1 = W_ih[r1];
        const float bias0 = b_ih[r0] + b_hh[r0];
        const float bias1 = b_ih[r1] + b_hh[r1];
        DW(0)  DW(1)  DW(2)  DW(3)  DW(4)  DW(5)  DW(6)  DW(7)
        DW(8)  DW(9)  DW(10) DW(11) DW(12) DW(13) DW(14) DW(15)
        DW(16) DW(17) DW(18) DW(19) DW(20) DW(21) DW(22) DW(23)
        DW(24) DW(25) DW(26) DW(27) DW(28) DW(29) DW(30) DW(31)
        const float gwl = gate_w[l & 31];
        const float gb = gate_b[0];

        // channel means for this batch (already scaled)
#pragma unroll
        for (int j = 0; j < 4; j++) {
            const int cch = j * 64 + l;
            cs[b][cch] = part[b * 256 + cch];
        }

        float h = 0.0f, cst = 0.0f;
        for (int t = 0; t < 256; t++) {
            const float inp = cs[b][t];
            float a0 = fmaf(inp, wih0, bias0), b0 = 0.f, c0 = 0.f, d0 = 0.f;
            float a1 = fmaf(inp, wih1, bias1), b1 = 0.f, c1 = 0.f, d1 = 0.f;
            GK(0,a0,a1)  GK(1,b0,b1)  GK(2,c0,c1)  GK(3,d0,d1)
            GK(4,a0,a1)  GK(5,b0,b1)  GK(6,c0,c1)  GK(7,d0,d1)
            GK(8,a0,a1)  GK(9,b0,b1)  GK(10,c0,c1) GK(11,d0,d1)
            GK(12,a0,a1) GK(13,b0,b1) GK(14,c0,c1) GK(15,d0,d1)
            GK(16,a0,a1) GK(17,b0,b1) GK(18,c0,c1) GK(19,d0,d1)
            GK(20,a0,a1) GK(21,b0,b1) GK(22,c0,c1) GK(23,d0,d1)
            GK(24,a0,a1) GK(25,b0,b1) GK(26,c0,c1) GK(27,d0,d1)
            GK(28,a0,a1) GK(29,b0,b1) GK(30,c0,c1) GK(31,d0,d1)
            const float z0 = (a0 + b0) + (c0 + d0);
            const float z1 = (a1 + b1) + (c1 + d1);
            float zf, zo;
#if __has_builtin(__builtin_amdgcn_permlane32_swap)
            {
                auto ra = __builtin_amdgcn_permlane32_swap(
                    __builtin_bit_cast(uint, z0), __builtin_bit_cast(uint, z0), false, false);
                auto rb = __builtin_amdgcn_permlane32_swap(
                    __builtin_bit_cast(uint, z1), __builtin_bit_cast(uint, z1), false, false);
                zf = __builtin_bit_cast(float, ra[1]);
                zo = __builtin_bit_cast(float, rb[1]);
            }
#else
            zf = __shfl_xor(z0, 32);
            zo = __shfl_xor(z1, 32);
#endif
            // valid in lanes<32 only (high lanes: finite garbage, never read)
            cst = sigf(zf) * cst + sigf(z0) * tanh_fast(z1);
            h = sigf(zo) * tanh_fast(cst);
            float p = h * gwl;   // inline gate reduce over lanes 0..31
            p += __shfl_xor(p, 1);  p += __shfl_xor(p, 2);  p += __shfl_xor(p, 4);
            p += __shfl_xor(p, 8);  p += __shfl_xor(p, 16);
            if (l == 0) gates[b * 256 + t] = sigf(p + gb);
        }
        __syncthreads();                 // all 4 waves done writing gates
        if (tid == 0) st_rel(flag, 1u);  // the ONLY store to the polled line
    }

    // ---------------- phase C: wait once, then scale own channel ----------------
    if (tid == 0) {
        while (ld_acq(flag) == 0u) __builtin_amdgcn_s_sleep(32);
        red[0] = gates[ch];              // acquire-ordered gate read
    }
    __syncthreads();
    const float g = red[0];

    {
        const f32x4* __restrict__ xi0 = (const f32x4*)x + off;
        const f32x4* __restrict__ xi1 = xi0 + 16384;
        f32x4* __restrict__ oi0 = (f32x4*)out + off;
        f32x4* __restrict__ oi1 = oi0 + 16384;
#pragma unroll
        for (int gr = 0; gr < 8; gr++) {
            f32x4 v0[8], v1[8];
#pragma unroll
            for (int u = 0; u < 8; u++) {
                v0[u] = xi0[gr * 2048 + u * 256 + tid];
                v1[u] = xi1[gr * 2048 + u * 256 + tid];
            }
#pragma unroll
            for (int u = 0; u < 8; u++) {
                v0[u] *= g;
                v1[u] *= g;
                __builtin_nontemporal_store(v0[u], &oi0[gr * 2048 + u * 256 + tid]);
                __builtin_nontemporal_store(v1[u], &oi1[gr * 2048 + u * 256 + tid]);
            }
        }
    }
}

extern "C" void kernel_launch(void* const* d_in, const int* in_sizes, int n_in,
                              void* d_out, int out_size, void* d_ws, size_t ws_size,
                              hipStream_t stream) {
    const float* x      = (const float*)d_in[0];
    const float* W_ih   = (const float*)d_in[1];   // (128,1)
    const float* W_hh   = (const float*)d_in[2];   // (128,32)
    const float* b_ih   = (const float*)d_in[3];   // (128,)
    const float* b_hh   = (const float*)d_in[4];   // (128,)
    const float* gate_w = (const float*)d_in[5];   // (1,32)
    const float* gate_b = (const float*)d_in[6];   // (1,)
    float* out = (float*)d_out;
    float* ws  = (float*)d_ws;

    // reset done/flag every call (capture-safe, deterministic)
    hipMemsetAsync(d_ws, 0, 256, stream);
    fused_kernel<<<1024, 256, 0, stream>>>(x, W_ih, W_hh, b_ih, b_hh,
                                           gate_w, gate_b, out, ws);
}

// Round 15
// 350.225 us; speedup vs baseline: 7.3894x; 2.3668x over previous
//
#include <hip/hip_runtime.h>

// Problem: x (B=4, C=256, D=32, H=64, W=64) fp32.
// 1) reflect-pad(2) + per-(b,c) mean  == weighted sum over original x
// 2) LSTMCell scan over C=256 channels (B=4, hidden=32, input=1)
// 3) gate[b,c] = sigmoid(h_c . gate_w + gate_b);  out = x * gate[b,c]
//
// R15: R8 structure (best: 378us) + SERPENTINE channel order for L3 locality
// across dispatches: mean walks channels DESCENDING, scale ASCENDING. In
// steady-state replay the previous scale pass ends on high channels -> mean
// starts there (L3 hits); mean ends on low channels -> scale starts there
// (L3 hits). NT stores keep `out` from polluting L3 (R8 vs R11: NT -14us).
// Fusion/spin variants R6/R10/R12/R14 all lost -- branch closed.

#define MEAN_DEN (1.0f / 166464.0f)   // 36*68*68

typedef unsigned int uint;
typedef float f32x4 __attribute__((ext_vector_type(4)));
typedef float f32x2 __attribute__((ext_vector_type(2)));

__device__ __forceinline__ float sigf(float x) {
    return 1.0f / (1.0f + __expf(-x));
}
__device__ __forceinline__ float tanh_fast(float x) {
    return fmaf(2.0f, sigf(2.0f * x), -1.0f);   // tanh(x) = 2*sigmoid(2x) - 1
}

// ---------- Kernel 1: weighted half-channel partial sums, DESCENDING ----------
// 2048 blocks (8/CU, 100% occupancy); 8 independent loads in flight/thread.
__global__ __launch_bounds__(256) void mean_kernel(const float* __restrict__ x,
                                                   float* __restrict__ part) {
    const int bid = 2047 - (int)blockIdx.x;        // descending walk over x
    const int ch = bid >> 1, half = bid & 1;
    const f32x4* __restrict__ p = (const f32x4*)x + (size_t)ch * 32768 + half * 16384;
    const int base = half * 16384;
    const int tid = threadIdx.x;

    float s0 = 0.0f, s1 = 0.0f, s2 = 0.0f, s3 = 0.0f;
#pragma unroll
    for (int g = 0; g < 8; g++) {
        f32x4 v[8];
#pragma unroll
        for (int u = 0; u < 8; u++) v[u] = p[g * 2048 + u * 256 + tid];
#pragma unroll
        for (int u = 0; u < 8; u++) {
            const int i = base + g * 2048 + u * 256 + tid;
            const int q = i & 15;             // f4 index within W-row
            const int hh = (i >> 4) & 63;
            const int d = i >> 10;
            float t = (v[u].x + v[u].y) + (v[u].z + v[u].w);
            if (q == 0 || q == 15) t += v[u].y + v[u].z;   // W 1,2,61,62 doubled
            const float wd = ((d == 1) | (d == 2) | (d == 29) | (d == 30)) ? 2.0f : 1.0f;
            const float wh = ((hh == 1) | (hh == 2) | (hh == 61) | (hh == 62)) ? 2.0f : 1.0f;
            const float w = wd * wh;
            if ((u & 3) == 0)      s0 = fmaf(w, t, s0);
            else if ((u & 3) == 1) s1 = fmaf(w, t, s1);
            else if ((u & 3) == 2) s2 = fmaf(w, t, s2);
            else                   s3 = fmaf(w, t, s3);
        }
    }
    float sum = (s0 + s1) + (s2 + s3);

    __shared__ float red[256];
    red[tid] = sum;
    __syncthreads();
    for (int s = 128; s > 0; s >>= 1) {
        if (tid < s) red[tid] += red[tid + s];
        __syncthreads();
    }
    if (tid == 0) part[bid] = red[0];
}

// ---------- Kernel 2: LSTM scan, 4 single-wave blocks ----------
#define RL(v, k) __builtin_bit_cast(float, \
    __builtin_amdgcn_readlane(__builtin_bit_cast(int, (v)), (k)))
#define DW(k) const float w0_##k = W_hh[r0 * 32 + (k)]; \
              const float w1_##k = W_hh[r1 * 32 + (k)];
#define GK(k, A0, A1) { const float hk = RL(h, k); \
                A0 = fmaf(hk, w0_##k, A0); A1 = fmaf(hk, w1_##k, A1); }

__global__ __launch_bounds__(64, 1) void lstm_kernel(
    const float* __restrict__ part,
    const float* __restrict__ W_ih, const float* __restrict__ W_hh,
    const float* __restrict__ b_ih, const float* __restrict__ b_hh,
    const float* __restrict__ gate_w, const float* __restrict__ gate_b,
    float* __restrict__ gates)
{
    __shared__ float cs[256];
    __shared__ float hist[257 * 33];     // stride-33: conflict-free epilogue reads

    const int b = blockIdx.x;            // batch 0..3
    const int l = threadIdx.x;           // lane 0..63
    const int r0 = l, r1 = l + 64;

    const float wih0 = W_ih[r0];
    const float wih1 = W_ih[r1];
    const float bias0 = b_ih[r0] + b_hh[r0];
    const float bias1 = b_ih[r1] + b_hh[r1];
    DW(0)  DW(1)  DW(2)  DW(3)  DW(4)  DW(5)  DW(6)  DW(7)
    DW(8)  DW(9)  DW(10) DW(11) DW(12) DW(13) DW(14) DW(15)
    DW(16) DW(17) DW(18) DW(19) DW(20) DW(21) DW(22) DW(23)
    DW(24) DW(25) DW(26) DW(27) DW(28) DW(29) DW(30) DW(31)

    // combine half-channel partials -> channel means for this batch
    const f32x2* __restrict__ p2 = (const f32x2*)part + b * 256;
#pragma unroll
    for (int j = 0; j < 4; j++) {
        const int cch = j * 64 + l;
        f32x2 pr = p2[cch];
        cs[cch] = (pr.x + pr.y) * MEAN_DEN;
    }

    float h = 0.0f, cstate = 0.0f;
    for (int t = 0; t < 256; t++) {
        const float inp = cs[t];
        float a0 = fmaf(inp, wih0, bias0), b0 = 0.f, c0 = 0.f, d0 = 0.f;
        float a1 = fmaf(inp, wih1, bias1), b1 = 0.f, c1 = 0.f, d1 = 0.f;
        GK(0,a0,a1)  GK(1,b0,b1)  GK(2,c0,c1)  GK(3,d0,d1)
        GK(4,a0,a1)  GK(5,b0,b1)  GK(6,c0,c1)  GK(7,d0,d1)
        GK(8,a0,a1)  GK(9,b0,b1)  GK(10,c0,c1) GK(11,d0,d1)
        GK(12,a0,a1) GK(13,b0,b1) GK(14,c0,c1) GK(15,d0,d1)
        GK(16,a0,a1) GK(17,b0,b1) GK(18,c0,c1) GK(19,d0,d1)
        GK(20,a0,a1) GK(21,b0,b1) GK(22,c0,c1) GK(23,d0,d1)
        GK(24,a0,a1) GK(25,b0,b1) GK(26,c0,c1) GK(27,d0,d1)
        GK(28,a0,a1) GK(29,b0,b1) GK(30,c0,c1) GK(31,d0,d1)
        const float z0 = (a0 + b0) + (c0 + d0);
        const float z1 = (a1 + b1) + (c1 + d1);
        float zf, zo;
#if __has_builtin(__builtin_amdgcn_permlane32_swap)
        {
            auto ra = __builtin_amdgcn_permlane32_swap(
                __builtin_bit_cast(uint, z0), __builtin_bit_cast(uint, z0), false, false);
            auto rb = __builtin_amdgcn_permlane32_swap(
                __builtin_bit_cast(uint, z1), __builtin_bit_cast(uint, z1), false, false);
            zf = __builtin_bit_cast(float, ra[1]);
            zo = __builtin_bit_cast(float, rb[1]);
        }
#else
        zf = __shfl_xor(z0, 32);
        zo = __shfl_xor(z1, 32);
#endif
        // valid in lanes<32 only (high lanes compute finite garbage, never read)
        cstate = sigf(zf) * cstate + sigf(z0) * tanh_fast(z1);
        h = sigf(zo) * tanh_fast(cstate);
        if (l < 32) hist[(t + 1) * 33 + l] = h;   // off critical path
    }

    // deferred output gates: lane handles t = l, l+64, l+128, l+192
    const float gb = gate_b[0];
#pragma unroll
    for (int chunk = 0; chunk < 4; chunk++) {
        const int t = chunk * 64 + l;
        const float* hrow = &hist[(t + 1) * 33];
        float s = gb;
#pragma unroll
        for (int k = 0; k < 32; k++) s = fmaf(hrow[k], gate_w[k], s);
        gates[b * 256 + t] = sigf(s);
    }
}

// ---------- Kernel 3: out = x * gate[ch], ASCENDING, NT stores ----------
__global__ __launch_bounds__(256) void scale_kernel(const float* __restrict__ x,
                                                    const float* __restrict__ gates,
                                                    float* __restrict__ out) {
    const int bid = blockIdx.x;                    // ascending walk over x
    const int ch = bid >> 1, half = bid & 1;
    const float g = gates[ch];
    const size_t off = (size_t)ch * 32768 + half * 16384;
    const f32x4* __restrict__ xi = (const f32x4*)x + off;
    f32x4* __restrict__ oi = (f32x4*)out + off;
    const int tid = threadIdx.x;
#pragma unroll
    for (int gr = 0; gr < 8; gr++) {
        f32x4 v[8];
#pragma unroll
        for (int u = 0; u < 8; u++) v[u] = xi[gr * 2048 + u * 256 + tid];
#pragma unroll
        for (int u = 0; u < 8; u++) {
            v[u] *= g;
            __builtin_nontemporal_store(v[u], &oi[gr * 2048 + u * 256 + tid]);
        }
    }
}

extern "C" void kernel_launch(void* const* d_in, const int* in_sizes, int n_in,
                              void* d_out, int out_size, void* d_ws, size_t ws_size,
                              hipStream_t stream) {
    const float* x      = (const float*)d_in[0];
    const float* W_ih   = (const float*)d_in[1];   // (128,1)
    const float* W_hh   = (const float*)d_in[2];   // (128,32)
    const float* b_ih   = (const float*)d_in[3];   // (128,)
    const float* b_hh   = (const float*)d_in[4];   // (128,)
    const float* gate_w = (const float*)d_in[5];   // (1,32)
    const float* gate_b = (const float*)d_in[6];   // (1,)
    float* out = (float*)d_out;

    float* part  = (float*)d_ws;          // 2048 floats: half-channel partials
    float* gates = (float*)d_ws + 2048;   // 1024 floats

    mean_kernel<<<2048, 256, 0, stream>>>(x, part);
    lstm_kernel<<<4, 64, 0, stream>>>(part, W_ih, W_hh, b_ih, b_hh,
                                      gate_w, gate_b, gates);
    scale_kernel<<<2048, 256, 0, stream>>>(x, gates, out);
}